// Round 3
// baseline (69.341 us; speedup 1.0000x reference)
//
#include <hip/hip_runtime.h>

#define ALPHA 0.3f
#define D 2
#define DH 5
#define NH 3

// e^{2z} = 2^(z * 2*log2(e))
__device__ __forceinline__ float exp2z(float z) {
    return __builtin_amdgcn_exp2f(z * 2.8853900817779268f);
}

// Given r = 1/(e^{2z}+1): tanh(z) = 1-2r; act = 0.3z+0.7t; act' = 1-0.7t^2
__device__ __forceinline__ void act_from_inv(float z, float r, float& h, float& d) {
    float t = fmaf(-2.0f, r, 1.0f);
    h = fmaf(0.3f, z, 0.7f * t);
    d = fmaf(-0.7f, t * t, 1.0f);
}

// Batched reciprocal of 5 values (Montgomery): 1 v_rcp + 12 v_mul instead of 5 v_rcp
__device__ __forceinline__ void batch_inv5(const float a[DH], float inv[DH]) {
    float p1 = a[0] * a[1];
    float p2 = p1 * a[2];
    float p3 = p2 * a[3];
    float p4 = p3 * a[4];
    float r  = __builtin_amdgcn_rcpf(p4);
    inv[4] = r * p3;  r = r * a[4];
    inv[3] = r * p2;  r = r * a[3];
    inv[2] = r * p1;  r = r * a[2];
    inv[1] = r * a[0]; inv[0] = r * a[1];
}

__global__ __launch_bounds__(256) void nnflow_kernel(
    const float4* __restrict__ xj4,
    const float* __restrict__ gW0,
    const float* __restrict__ gWs,
    const float* __restrict__ gWout,
    float4* __restrict__ out4,
    int nquads)
{
    int t = blockIdx.x * blockDim.x + threadIdx.x;
    if (t >= nquads) return;

    // ---- weights: uniform pointers + constant indices -> scalar s_loads ----
    float w0[DH][D];
    #pragma unroll
    for (int k = 0; k < DH; ++k)
        #pragma unroll
        for (int j = 0; j < D; ++j)
            w0[k][j] = gW0[k * D + j];

    float ws[NH][DH][DH];
    #pragma unroll
    for (int i = 0; i < NH; ++i)
        #pragma unroll
        for (int k = 0; k < DH; ++k)
            #pragma unroll
            for (int j = 0; j < DH; ++j)
                ws[i][k][j] = gWs[(i * DH + k) * DH + j];

    float wo[D][DH];
    #pragma unroll
    for (int r = 0; r < D; ++r)
        #pragma unroll
        for (int j = 0; j < DH; ++j)
            wo[r][j] = gWout[r * DH + j];

    // ---- 4 samples = 12 floats = 3 float4, perfectly coalesced ----
    float4 v0 = xj4[(size_t)t * 3 + 0];
    float4 v1 = xj4[(size_t)t * 3 + 1];
    float4 v2 = xj4[(size_t)t * 3 + 2];

    float xs[4][3] = {
        {v0.x, v0.y, v0.z},
        {v0.w, v1.x, v1.y},
        {v1.z, v1.w, v2.x},
        {v2.y, v2.z, v2.w}
    };
    float os[4][3];

    #pragma unroll
    for (int s = 0; s < 4; ++s) {
        float x0 = xs[s][0], x1 = xs[s][1], lj = xs[s][2];

        // ---- layer 0: z = W0 x ----
        float zv[DH], av[DH], inv[DH];
        #pragma unroll
        for (int k = 0; k < DH; ++k) {
            zv[k] = fmaf(w0[k][0], x0, w0[k][1] * x1);
            av[k] = exp2z(zv[k]) + 1.0f;
        }
        batch_inv5(av, inv);

        float h[DH], J0[DH], J1[DH];
        #pragma unroll
        for (int k = 0; k < DH; ++k) {
            float hk, dk;
            act_from_inv(zv[k], inv[k], hk, dk);
            h[k]  = hk;
            J0[k] = dk * w0[k][0];
            J1[k] = dk * w0[k][1];
        }

        // ---- hidden layers ----
        #pragma unroll
        for (int i = 0; i < NH; ++i) {
            float jt0[DH], jt1[DH];
            #pragma unroll
            for (int k = 0; k < DH; ++k) {
                float z = 0.f, j0 = 0.f, j1 = 0.f;
                #pragma unroll
                for (int j = 0; j < DH; ++j) {
                    float w = ws[i][k][j];
                    z  = fmaf(w, h[j],  z);
                    j0 = fmaf(w, J0[j], j0);
                    j1 = fmaf(w, J1[j], j1);
                }
                zv[k] = z;
                av[k] = exp2z(z) + 1.0f;
                jt0[k] = j0;
                jt1[k] = j1;
            }
            batch_inv5(av, inv);
            #pragma unroll
            for (int k = 0; k < DH; ++k) {
                float hk, dk;
                act_from_inv(zv[k], inv[k], hk, dk);
                h[k]  = hk;
                J0[k] = dk * jt0[k];
                J1[k] = dk * jt1[k];
            }
        }

        // ---- output layer (2 neurons, paired reciprocal) ----
        float zo[2], jo0[2], jo1[2];
        #pragma unroll
        for (int r = 0; r < 2; ++r) {
            float z = 0.f, j0 = 0.f, j1 = 0.f;
            #pragma unroll
            for (int j = 0; j < DH; ++j) {
                float w = wo[r][j];
                z  = fmaf(w, h[j],  z);
                j0 = fmaf(w, J0[j], j0);
                j1 = fmaf(w, J1[j], j1);
            }
            zo[r] = z; jo0[r] = j0; jo1[r] = j1;
        }
        float a0 = exp2z(zo[0]) + 1.0f;
        float a1 = exp2z(zo[1]) + 1.0f;
        float rp = __builtin_amdgcn_rcpf(a0 * a1);
        float i0 = rp * a1;
        float i1 = rp * a0;

        float y0, d0, y1, d1;
        act_from_inv(zo[0], i0, y0, d0);
        act_from_inv(zo[1], i1, y1, d1);

        float det = fabsf(d0 * jo0[0] * (d1 * jo1[1]) - d0 * jo1[0] * (d1 * jo0[1]));
        float ld = __builtin_amdgcn_logf(det) * 0.6931471805599453f;

        os[s][0] = y0;
        os[s][1] = y1;
        os[s][2] = lj + ld;
    }

    out4[(size_t)t * 3 + 0] = make_float4(os[0][0], os[0][1], os[0][2], os[1][0]);
    out4[(size_t)t * 3 + 1] = make_float4(os[1][1], os[1][2], os[2][0], os[2][1]);
    out4[(size_t)t * 3 + 2] = make_float4(os[2][2], os[3][0], os[3][1], os[3][2]);
}

extern "C" void kernel_launch(void* const* d_in, const int* in_sizes, int n_in,
                              void* d_out, int out_size, void* d_ws, size_t ws_size,
                              hipStream_t stream) {
    const float* xj   = (const float*)d_in[0];
    const float* W0   = (const float*)d_in[1];
    const float* Ws   = (const float*)d_in[2];
    const float* Wout = (const float*)d_in[3];
    float* out = (float*)d_out;

    int n = in_sizes[0] / (D + 1);   // 4194304
    int nquads = n / 4;

    dim3 block(256);
    dim3 grid((nquads + block.x - 1) / block.x);
    nnflow_kernel<<<grid, block, 0, stream>>>(
        (const float4*)xj, W0, Ws, Wout, (float4*)out, nquads);
}